// Round 5
// baseline (239.649 us; speedup 1.0000x reference)
//
#include <hip/hip_runtime.h>
#include <hip/hip_bf16.h>

// Problem constants (fixed by the reference module)
static constexpr int B_  = 2;
static constexpr int N_  = 4096;
static constexpr int D_  = 512;
static constexpr int H_  = 8;
static constexpr int P_  = 9;
static constexpr int GH_ = 16;   // grid h
static constexpr int GW_ = 256;  // grid w
static constexpr int M_  = B_ * N_;  // 8192 tokens

typedef __attribute__((ext_vector_type(8))) short bf16x8;
typedef __attribute__((ext_vector_type(4))) float f32x4;

__device__ __forceinline__ unsigned short f2b(float f) {
    __hip_bfloat16 h = __float2bfloat16(f);  // round-to-nearest
    return *reinterpret_cast<unsigned short*>(&h);
}
__device__ __forceinline__ float b2f(unsigned short u) {
    return __uint_as_float(((unsigned int)u) << 16);
}
__device__ __forceinline__ float b2f_lo(unsigned int u) { return __uint_as_float(u << 16); }
__device__ __forceinline__ float b2f_hi(unsigned int u) { return __uint_as_float(u & 0xffff0000u); }

// ---------------------------------------------------------------------------
// Cast fp32 -> bf16. Ranges (float4 units):
//   x (dual hi/lo) 1048576 | Wq 65536 | Wkv 131072 | Wo 65536 |
//   Woff (dual) 18432 | zero-pad woff rows 144..255: 14336
__global__ __launch_bounds__(256) void cast_multi(
    const float* __restrict__ x,   const float* __restrict__ wq,
    const float* __restrict__ wkv, const float* __restrict__ wo,
    const float* __restrict__ woff,
    unsigned short* __restrict__ x_hi, unsigned short* __restrict__ x_lo,
    unsigned short* __restrict__ wqkv, unsigned short* __restrict__ wob,
    unsigned short* __restrict__ woff_hi, unsigned short* __restrict__ woff_lo) {
    int g = blockIdx.x * 256 + threadIdx.x;

    if (g < 1048576) {  // x -> hi + lo
        float4 v = reinterpret_cast<const float4*>(x)[g];
        ushort4 hi, lo;
        hi.x = f2b(v.x); hi.y = f2b(v.y); hi.z = f2b(v.z); hi.w = f2b(v.w);
        lo.x = f2b(v.x - b2f(hi.x)); lo.y = f2b(v.y - b2f(hi.y));
        lo.z = f2b(v.z - b2f(hi.z)); lo.w = f2b(v.w - b2f(hi.w));
        reinterpret_cast<ushort4*>(x_hi)[g] = hi;
        reinterpret_cast<ushort4*>(x_lo)[g] = lo;
        return;
    }
    g -= 1048576;
    if (g < 65536) {  // Wq -> wqkv rows 0..511
        float4 v = reinterpret_cast<const float4*>(wq)[g];
        ushort4 o; o.x = f2b(v.x); o.y = f2b(v.y); o.z = f2b(v.z); o.w = f2b(v.w);
        reinterpret_cast<ushort4*>(wqkv)[g] = o;
        return;
    }
    g -= 65536;
    if (g < 131072) {  // Wkv -> wqkv rows 512..1535
        float4 v = reinterpret_cast<const float4*>(wkv)[g];
        ushort4 o; o.x = f2b(v.x); o.y = f2b(v.y); o.z = f2b(v.z); o.w = f2b(v.w);
        reinterpret_cast<ushort4*>(wqkv)[65536 + g] = o;
        return;
    }
    g -= 131072;
    if (g < 65536) {  // Wo
        float4 v = reinterpret_cast<const float4*>(wo)[g];
        ushort4 o; o.x = f2b(v.x); o.y = f2b(v.y); o.z = f2b(v.z); o.w = f2b(v.w);
        reinterpret_cast<ushort4*>(wob)[g] = o;
        return;
    }
    g -= 65536;
    if (g < 18432) {  // Woff rows 0..143 -> hi + lo
        float4 v = reinterpret_cast<const float4*>(woff)[g];
        ushort4 hi, lo;
        hi.x = f2b(v.x); hi.y = f2b(v.y); hi.z = f2b(v.z); hi.w = f2b(v.w);
        lo.x = f2b(v.x - b2f(hi.x)); lo.y = f2b(v.y - b2f(hi.y));
        lo.z = f2b(v.z - b2f(hi.z)); lo.w = f2b(v.w - b2f(hi.w));
        reinterpret_cast<ushort4*>(woff_hi)[g] = hi;
        reinterpret_cast<ushort4*>(woff_lo)[g] = lo;
        return;
    }
    g -= 18432;
    // zero-pad rows 144..255 of woff_hi / woff_lo (g in [0, 14336))
    ushort4 z = {0, 0, 0, 0};
    reinterpret_cast<ushort4*>(woff_hi)[18432 + g] = z;
    reinterpret_cast<ushort4*>(woff_lo)[18432 + g] = z;
}

// ---------------------------------------------------------------------------
// MFMA K-loop, BK=64 (two m97-pattern 32-chunks per iteration, halved barrier
// count). 128x128 tile, 4 waves x 4x4 frags of 16x16x32 bf16 MFMA.
// As/Bs: 2 chunks x [128][32] shorts = 8192 shorts (16 KB) each.
__device__ __forceinline__ void gemm_seg(const unsigned short* __restrict__ A,
                                         const unsigned short* __restrict__ W,
                                         int m0, int n0, int K,
                                         short* As, short* Bs,
                                         f32x4 (&acc)[4][4], int wave, int lane) {
    // per-call slot (c = 0,1): gi = c*256 + wave*64 + lane, r = gi>>2, col=(gi&3)*8
    const int gi0 = wave * 64 + lane;
    const int gi1 = gi0 + 256;
    const int r0 = gi0 >> 2, c0 = (gi0 & 3) * 8;
    const int r1 = gi1 >> 2, c1 = (gi1 & 3) * 8;

    const unsigned short* pa0 = A + (size_t)(m0 + r0) * K + c0;
    const unsigned short* pa1 = A + (size_t)(m0 + r1) * K + c1;
    const unsigned short* pw0 = W + (size_t)(n0 + r0) * K + c0;
    const unsigned short* pw1 = W + (size_t)(n0 + r1) * K + c1;

    // wave-uniform LDS bases (ushort units): chunk t at t*4096, call c at c*2048
    short* ldsA0 = As + wave * 512;
    short* ldsA1 = As + wave * 512 + 2048;
    short* ldsB0 = Bs + wave * 512;
    short* ldsB1 = Bs + wave * 512 + 2048;

    const int wm = wave & 1, wn = wave >> 1;
    const int fr = lane & 15;
    const int fk = (lane >> 4) * 8;

    for (int k0 = 0; k0 < K; k0 += 64) {
#pragma unroll
        for (int t = 0; t < 2; ++t) {
            __builtin_amdgcn_global_load_lds(
                (const __attribute__((address_space(1))) void*)(pa0 + k0 + t * 32),
                (__attribute__((address_space(3))) void*)(ldsA0 + t * 4096), 16, 0, 0);
            __builtin_amdgcn_global_load_lds(
                (const __attribute__((address_space(1))) void*)(pa1 + k0 + t * 32),
                (__attribute__((address_space(3))) void*)(ldsA1 + t * 4096), 16, 0, 0);
            __builtin_amdgcn_global_load_lds(
                (const __attribute__((address_space(1))) void*)(pw0 + k0 + t * 32),
                (__attribute__((address_space(3))) void*)(ldsB0 + t * 4096), 16, 0, 0);
            __builtin_amdgcn_global_load_lds(
                (const __attribute__((address_space(1))) void*)(pw1 + k0 + t * 32),
                (__attribute__((address_space(3))) void*)(ldsB1 + t * 4096), 16, 0, 0);
        }
        __syncthreads();

        bf16x8 af[4][2], bfr[4][2];
#pragma unroll
        for (int i = 0; i < 4; ++i)
#pragma unroll
            for (int t = 0; t < 2; ++t)
                af[i][t] = *reinterpret_cast<const bf16x8*>(
                    &As[t * 4096 + (wm * 64 + i * 16 + fr) * 32 + fk]);
#pragma unroll
        for (int j = 0; j < 4; ++j)
#pragma unroll
            for (int t = 0; t < 2; ++t)
                bfr[j][t] = *reinterpret_cast<const bf16x8*>(
                    &Bs[t * 4096 + (wn * 64 + j * 16 + fr) * 32 + fk]);
#pragma unroll
        for (int i = 0; i < 4; ++i)
#pragma unroll
            for (int j = 0; j < 4; ++j) {
                acc[i][j] = __builtin_amdgcn_mfma_f32_16x16x32_bf16(
                    af[i][0], bfr[j][0], acc[i][j], 0, 0, 0);
                acc[i][j] = __builtin_amdgcn_mfma_f32_16x16x32_bf16(
                    af[i][1], bfr[j][1], acc[i][j], 0, 0, 0);
            }
        __syncthreads();
    }
}

// MODE 0: plain fp32 store, stride 512 (out GEMM).
// MODE 1: qkv split: n<512 -> bf16 q (pre-scaled by 0.125); n in [512,1024) ->
//         bf16 k slot; n in [1024,1536) -> bf16 v slot (interleaved pairs).
template <int MODE>
__global__ __launch_bounds__(256) void gemm_mfma(const unsigned short* __restrict__ A,
                                                 const unsigned short* __restrict__ W,
                                                 const float* __restrict__ bias0,
                                                 const float* __restrict__ bias1,
                                                 void* __restrict__ out0,
                                                 void* __restrict__ out1,
                                                 int K) {
    __shared__ short As[8192];
    __shared__ short Bs[8192];
    const int t = threadIdx.x;
    const int wave = t >> 6, lane = t & 63;
    const int m0 = blockIdx.y * 128;
    const int n0 = blockIdx.x * 128;

    f32x4 acc[4][4] = {};
    gemm_seg(A, W, m0, n0, K, As, Bs, acc, wave, lane);

    const int wm = wave & 1, wn = wave >> 1;
    const int ecol = lane & 15;
    const int erow = (lane >> 4) * 4;
#pragma unroll
    for (int i = 0; i < 4; ++i) {
#pragma unroll
        for (int j = 0; j < 4; ++j) {
#pragma unroll
            for (int r = 0; r < 4; ++r) {
                const int m = m0 + wm * 64 + i * 16 + erow + r;
                const int n = n0 + wn * 64 + j * 16 + ecol;
                const float v = acc[i][j][r];
                if (MODE == 0) {
                    ((float*)out0)[(size_t)m * 512 + n] = v + bias0[n];
                } else {
                    if (n < 512)
                        ((unsigned short*)out0)[(size_t)m * 512 + n] =
                            f2b((v + bias0[n]) * 0.125f);
                    else if (n < 1024)
                        ((unsigned short*)out1)[(size_t)m * 1024 + 2 * (n - 512)] =
                            f2b(v + bias1[n - 512]);
                    else
                        ((unsigned short*)out1)[(size_t)m * 1024 + 2 * (n - 1024) + 1] =
                            f2b(v + bias1[n - 512]);
                }
            }
        }
    }
}

// Offset head: bf16x3 (x_hi@W_hi + x_hi@W_lo + x_lo@W_hi) ~ fp32 precision.
// Raw (acc+bias) fp32 store; tanh deferred to samp_prep. Nout=144 (padded 256).
__global__ __launch_bounds__(256) void gemm_off3(const unsigned short* __restrict__ Ah,
                                                 const unsigned short* __restrict__ Al,
                                                 const unsigned short* __restrict__ Wh,
                                                 const unsigned short* __restrict__ Wl,
                                                 const float* __restrict__ bias,
                                                 float* __restrict__ Y) {
    __shared__ short As[8192];
    __shared__ short Bs[8192];
    const int t = threadIdx.x;
    const int wave = t >> 6, lane = t & 63;
    const int m0 = blockIdx.y * 128;
    const int n0 = blockIdx.x * 128;

    f32x4 acc[4][4] = {};
    gemm_seg(Ah, Wh, m0, n0, 512, As, Bs, acc, wave, lane);
    gemm_seg(Ah, Wl, m0, n0, 512, As, Bs, acc, wave, lane);
    gemm_seg(Al, Wh, m0, n0, 512, As, Bs, acc, wave, lane);

    const int wm = wave & 1, wn = wave >> 1;
    const int ecol = lane & 15;
    const int erow = (lane >> 4) * 4;
#pragma unroll
    for (int i = 0; i < 4; ++i) {
#pragma unroll
        for (int j = 0; j < 4; ++j) {
            const int n = n0 + wn * 64 + j * 16 + ecol;
            if (n < 144) {
#pragma unroll
                for (int r = 0; r < 4; ++r) {
                    const int m = m0 + wm * 64 + i * 16 + erow + r;
                    Y[(size_t)m * 144 + n] = acc[i][j][r] + bias[n];
                }
            }
        }
    }
}

// ---------------------------------------------------------------------------
// Sampling-parameter precompute: one thread per (b,h,n,p).
// pid = ((b*H + h)*N + n)*P + p.  Reads raw offset logits, applies tanh*4,
// emits 4 bilinear weights (validity-folded) + 4 clamped row offsets
// (ushort-units into kv2, hh*128 folded in).
__global__ __launch_bounds__(256) void samp_prep(const float* __restrict__ off_acc,
                                                 float4* __restrict__ sampw,
                                                 int4* __restrict__ sampo) {
    const int pid = blockIdx.x * 256 + threadIdx.x;  // [0, 589824)
    int tmp = pid;
    const int p  = tmp % P_;  tmp /= P_;
    const int n  = tmp & (N_ - 1);
    const int bh = tmp >> 12;
    const int hh = bh & 7;
    const int b  = bh >> 3;

    const size_t tok = (size_t)b * N_ + n;
    const float2 o2 = *reinterpret_cast<const float2*>(
        off_acc + tok * 144 + hh * 18 + 2 * p);
    const float dx = tanhf(o2.x) * 4.0f;
    const float dy = tanhf(o2.y) * 4.0f;
    const float sx = (float)(n & (GW_ - 1)) + dx;
    const float sy = (float)(n >> 8) + dy;
    const float x0f = floorf(sx), y0f = floorf(sy);
    const int x0 = (int)x0f, y0 = (int)y0f;
    const float wx1 = sx - x0f, wy1 = sy - y0f;
    const float wx0 = 1.0f - wx1, wy0 = 1.0f - wy1;

    float4 w;
    int4 ro;
    {
        const int xi = x0, yi = y0;
        const bool v = (xi >= 0) & (xi < GW_) & (yi >= 0) & (yi < GH_);
        w.x = v ? wx0 * wy0 : 0.0f;
        const int xc = xi < 0 ? 0 : (xi > 255 ? 255 : xi);
        const int yc = yi < 0 ? 0 : (yi > 15 ? 15 : yi);
        ro.x = (yc * GW_ + xc) * 1024 + hh * 128;
    }
    {
        const int xi = x0 + 1, yi = y0;
        const bool v = (xi >= 0) & (xi < GW_) & (yi >= 0) & (yi < GH_);
        w.y = v ? wx1 * wy0 : 0.0f;
        const int xc = xi < 0 ? 0 : (xi > 255 ? 255 : xi);
        const int yc = yi < 0 ? 0 : (yi > 15 ? 15 : yi);
        ro.y = (yc * GW_ + xc) * 1024 + hh * 128;
    }
    {
        const int xi = x0, yi = y0 + 1;
        const bool v = (xi >= 0) & (xi < GW_) & (yi >= 0) & (yi < GH_);
        w.z = v ? wx0 * wy1 : 0.0f;
        const int xc = xi < 0 ? 0 : (xi > 255 ? 255 : xi);
        const int yc = yi < 0 ? 0 : (yi > 15 ? 15 : yi);
        ro.z = (yc * GW_ + xc) * 1024 + hh * 128;
    }
    {
        const int xi = x0 + 1, yi = y0 + 1;
        const bool v = (xi >= 0) & (xi < GW_) & (yi >= 0) & (yi < GH_);
        w.w = v ? wx1 * wy1 : 0.0f;
        const int xc = xi < 0 ? 0 : (xi > 255 ? 255 : xi);
        const int yc = yi < 0 ? 0 : (yi > 15 ? 15 : yi);
        ro.w = (yc * GW_ + xc) * 1024 + hh * 128;
    }
    sampw[pid] = w;
    sampo[pid] = ro;
}

// ---------------------------------------------------------------------------
// One wave = 2 consecutive tokens of one (b, head); half-wave per token, lane j
// covers channels 2j,2j+1 via one uint2 (bf16 k,v interleaved: k0,v0,k1,v1).
// q_bf pre-scaled by HD^-0.5. Sampling params precomputed.
__global__ __launch_bounds__(256) void attn_sample(const unsigned short* __restrict__ q_bf,
                                                   const float4* __restrict__ sampw,
                                                   const int4* __restrict__ sampo,
                                                   const unsigned short* __restrict__ kv2,
                                                   unsigned short* __restrict__ a_bf) {
    const int lane = threadIdx.x & 63;
    const int half = lane >> 5;
    const int j    = lane & 31;
    const int wid  = blockIdx.x * 4 + (threadIdx.x >> 6);  // [0, 32768)
    const int b    = wid >> 14;
    const int hh   = (wid >> 11) & 7;
    const int np   = wid & 2047;
    const int n    = np * 2 + half;

    const size_t tok = (size_t)b * N_ + n;
    const unsigned int qp = *reinterpret_cast<const unsigned int*>(
        q_bf + tok * 512 + hh * 64 + 2 * j);
    const float q0 = b2f_lo(qp);  // already * 0.125
    const float q1 = b2f_hi(qp);

    const int pbase = (((b * H_ + hh) * N_ + n)) * P_;
    const unsigned short* kvbase = kv2 + (size_t)b * (N_ * 1024) + 4 * j;

    float lg[9], s0[9], s1[9];
    float mx = -1e30f;

#pragma unroll
    for (int p = 0; p < P_; ++p) {
        const float4 w = sampw[pbase + p];
        const int4 ro = sampo[pbase + p];
        float k0 = 0.f, k1 = 0.f, v0 = 0.f, v1 = 0.f;
        {
            const uint2 kv = *reinterpret_cast<const uint2*>(kvbase + ro.x);
            k0 = fmaf(w.x, b2f_lo(kv.x), k0); v0 = fmaf(w.x, b2f_hi(kv.x), v0);
            k1 = fmaf(w.x, b2f_lo(kv.y), k1); v1 = fmaf(w.x, b2f_hi(kv.y), v1);
        }
        {
            const uint2 kv = *reinterpret_cast<const uint2*>(kvbase + ro.y);
            k0 = fmaf(w.y, b2f_lo(kv.x), k0); v0 = fmaf(w.y, b2f_hi(kv.x), v0);
            k1 = fmaf(w.y, b2f_lo(kv.y), k1); v1 = fmaf(w.y, b2f_hi(kv.y), v1);
        }
        {
            const uint2 kv = *reinterpret_cast<const uint2*>(kvbase + ro.z);
            k0 = fmaf(w.z, b2f_lo(kv.x), k0); v0 = fmaf(w.z, b2f_hi(kv.x), v0);
            k1 = fmaf(w.z, b2f_lo(kv.y), k1); v1 = fmaf(w.z, b2f_hi(kv.y), v1);
        }
        {
            const uint2 kv = *reinterpret_cast<const uint2*>(kvbase + ro.w);
            k0 = fmaf(w.w, b2f_lo(kv.x), k0); v0 = fmaf(w.w, b2f_hi(kv.x), v0);
            k1 = fmaf(w.w, b2f_lo(kv.y), k1); v1 = fmaf(w.w, b2f_hi(kv.y), v1);
        }
        float ts = fmaf(q0, k0, q1 * k1);
#pragma unroll
        for (int s = 16; s > 0; s >>= 1) ts += __shfl_xor(ts, s, 64);  // 32-lane half
        lg[p] = ts;
        s0[p] = v0;
        s1[p] = v1;
        mx = fmaxf(mx, lg[p]);
    }

    float ssum = 0.f, o0 = 0.f, o1 = 0.f;
#pragma unroll
    for (int p = 0; p < P_; ++p) {
        const float e = __expf(lg[p] - mx);
        ssum += e;
        o0 = fmaf(e, s0[p], o0);
        o1 = fmaf(e, s1[p], o1);
    }
    const float rs = 1.0f / ssum;
    const unsigned int pack =
        (unsigned int)f2b(o0 * rs) | ((unsigned int)f2b(o1 * rs) << 16);
    *reinterpret_cast<unsigned int*>(a_bf + tok * 512 + hh * 64 + 2 * j) = pack;
}

// ---------------------------------------------------------------------------
extern "C" void kernel_launch(void* const* d_in, const int* in_sizes, int n_in,
                              void* d_out, int out_size, void* d_ws, size_t ws_size,
                              hipStream_t stream) {
    const float* x    = (const float*)d_in[0];
    const float* bq   = (const float*)d_in[2];
    const float* Woff = (const float*)d_in[3];
    const float* boff = (const float*)d_in[4];
    const float* bkv  = (const float*)d_in[6];
    const float* bo   = (const float*)d_in[8];
    float* out = (float*)d_out;

    // Workspace layout (~68 MB)
    char* ws = (char*)d_ws;
    unsigned short* q_bf    = (unsigned short*)ws; ws += (size_t)M_ * 512 * 2;    // 8 MB
    float*          off_acc = (float*)ws;          ws += (size_t)M_ * 144 * 4;    // 4.7 MB
    unsigned short* kv2     = (unsigned short*)ws; ws += (size_t)M_ * 1024 * 2;   // 16.8 MB
    unsigned short* xlo_abf = (unsigned short*)ws; ws += (size_t)M_ * 512 * 2;    // 8 MB (x_lo, then a_bf)
    unsigned short* x_hi    = (unsigned short*)ws; ws += (size_t)M_ * 512 * 2;    // 8 MB
    unsigned short* wqkv    = (unsigned short*)ws; ws += (size_t)1536 * 512 * 2;
    unsigned short* wob     = (unsigned short*)ws; ws += (size_t)512 * 512 * 2;
    unsigned short* woff_hi = (unsigned short*)ws; ws += (size_t)256 * 512 * 2;
    unsigned short* woff_lo = (unsigned short*)ws; ws += (size_t)256 * 512 * 2;
    float4*         sampw   = (float4*)ws;         ws += (size_t)M_ * H_ * P_ * 16;  // 9.4 MB
    int4*           sampo   = (int4*)ws;           ws += (size_t)M_ * H_ * P_ * 16;  // 9.4 MB

    const dim3 blk(256);

    // 0) casts (x -> hi/lo, weights -> bf16, zero-pad woff)
    cast_multi<<<dim3(5248), blk, 0, stream>>>(
        x, (const float*)d_in[1], (const float*)d_in[5], (const float*)d_in[7], Woff,
        x_hi, xlo_abf, wqkv, wob, woff_hi, woff_lo);

    // 1) raw offset logits (bf16x3 GEMM + boff), tanh deferred
    gemm_off3<<<dim3(2, M_ / 128), blk, 0, stream>>>(
        x_hi, xlo_abf, woff_hi, woff_lo, boff, off_acc);

    // 2) fused q + kv GEMM (N=1536, 768 blocks); q pre-scaled, kv -> bf16 pairs
    gemm_mfma<1><<<dim3(12, M_ / 128), blk, 0, stream>>>(
        x_hi, wqkv, bq, bkv, q_bf, kv2, D_);

    // 3) sampling-parameter precompute (tanh + bilinear weights + offsets)
    samp_prep<<<dim3(M_ * H_ * P_ / 256), blk, 0, stream>>>(off_acc, sampw, sampo);

    // 4) sampling + attention (2 tokens/wave) -> a_bf (aliases x_lo, now dead)
    attn_sample<<<dim3((B_ * H_ * N_) / 8), blk, 0, stream>>>(
        q_bf, sampw, sampo, kv2, xlo_abf);

    // 5) out = attn @ Wo^T + bo (fp32 out)
    gemm_mfma<0><<<dim3(4, M_ / 128), blk, 0, stream>>>(
        xlo_abf, wob, bo, nullptr, out, nullptr, D_);
}

// Round 6
// 221.632 us; speedup vs baseline: 1.0813x; 1.0813x over previous
//
#include <hip/hip_runtime.h>
#include <hip/hip_bf16.h>

// Problem constants (fixed by the reference module)
static constexpr int B_  = 2;
static constexpr int N_  = 4096;
static constexpr int D_  = 512;
static constexpr int H_  = 8;
static constexpr int P_  = 9;
static constexpr int GH_ = 16;   // grid h
static constexpr int GW_ = 256;  // grid w
static constexpr int M_  = B_ * N_;  // 8192 tokens

typedef __attribute__((ext_vector_type(8))) short bf16x8;
typedef __attribute__((ext_vector_type(4))) float f32x4;

__device__ __forceinline__ unsigned short f2b(float f) {
    __hip_bfloat16 h = __float2bfloat16(f);  // round-to-nearest
    return *reinterpret_cast<unsigned short*>(&h);
}
__device__ __forceinline__ float b2f(unsigned short u) {
    return __uint_as_float(((unsigned int)u) << 16);
}
__device__ __forceinline__ float b2f_lo(unsigned int u) { return __uint_as_float(u << 16); }
__device__ __forceinline__ float b2f_hi(unsigned int u) { return __uint_as_float(u & 0xffff0000u); }

// ---------------------------------------------------------------------------
// Cast fp32 -> bf16 and build the fused weight wall (2304 rows x 512):
//   rows    0..511  Wq
//   rows  512..1535 Wkv
//   rows 1536..1679 Woff_hi (+pad to 1791)
//   rows 1792..1935 Woff_lo (+pad to 2047)
//   rows 2048..2191 Woff_hi dup (+pad to 2303)
// Ranges (ushort4/float4 units): x dual 1048576 | wq 65536 | wkv 131072 |
//   wo 65536 | woff triple 18432 | pads 43008.  Total 1372160 -> 5360 blocks.
__global__ __launch_bounds__(256) void cast_multi(
    const float* __restrict__ x,   const float* __restrict__ wq,
    const float* __restrict__ wkv, const float* __restrict__ wo,
    const float* __restrict__ woff,
    unsigned short* __restrict__ x_hi, unsigned short* __restrict__ x_lo,
    unsigned short* __restrict__ wall, unsigned short* __restrict__ wob) {
    int g = blockIdx.x * 256 + threadIdx.x;

    if (g < 1048576) {  // x -> hi + lo
        float4 v = reinterpret_cast<const float4*>(x)[g];
        ushort4 hi, lo;
        hi.x = f2b(v.x); hi.y = f2b(v.y); hi.z = f2b(v.z); hi.w = f2b(v.w);
        lo.x = f2b(v.x - b2f(hi.x)); lo.y = f2b(v.y - b2f(hi.y));
        lo.z = f2b(v.z - b2f(hi.z)); lo.w = f2b(v.w - b2f(hi.w));
        reinterpret_cast<ushort4*>(x_hi)[g] = hi;
        reinterpret_cast<ushort4*>(x_lo)[g] = lo;
        return;
    }
    g -= 1048576;
    if (g < 65536) {  // Wq -> wall rows 0..511
        float4 v = reinterpret_cast<const float4*>(wq)[g];
        ushort4 o; o.x = f2b(v.x); o.y = f2b(v.y); o.z = f2b(v.z); o.w = f2b(v.w);
        reinterpret_cast<ushort4*>(wall)[g] = o;
        return;
    }
    g -= 65536;
    if (g < 131072) {  // Wkv -> wall rows 512..1535
        float4 v = reinterpret_cast<const float4*>(wkv)[g];
        ushort4 o; o.x = f2b(v.x); o.y = f2b(v.y); o.z = f2b(v.z); o.w = f2b(v.w);
        reinterpret_cast<ushort4*>(wall)[65536 + g] = o;
        return;
    }
    g -= 131072;
    if (g < 65536) {  // Wo -> wob
        float4 v = reinterpret_cast<const float4*>(wo)[g];
        ushort4 o; o.x = f2b(v.x); o.y = f2b(v.y); o.z = f2b(v.z); o.w = f2b(v.w);
        reinterpret_cast<ushort4*>(wob)[g] = o;
        return;
    }
    g -= 65536;
    if (g < 18432) {  // Woff rows 0..143 -> wall hi (1536), lo (1792), hi-dup (2048)
        float4 v = reinterpret_cast<const float4*>(woff)[g];
        ushort4 hi, lo;
        hi.x = f2b(v.x); hi.y = f2b(v.y); hi.z = f2b(v.z); hi.w = f2b(v.w);
        lo.x = f2b(v.x - b2f(hi.x)); lo.y = f2b(v.y - b2f(hi.y));
        lo.z = f2b(v.z - b2f(hi.z)); lo.w = f2b(v.w - b2f(hi.w));
        reinterpret_cast<ushort4*>(wall)[196608 + g] = hi;
        reinterpret_cast<ushort4*>(wall)[229376 + g] = lo;
        reinterpret_cast<ushort4*>(wall)[262144 + g] = hi;
        return;
    }
    g -= 18432;
    // zero pads: rows 1680..1791 / 1936..2047 / 2192..2303 (14336 units each)
    const int which = g / 14336;
    const int idx   = g - which * 14336;
    ushort4 z = {0, 0, 0, 0};
    reinterpret_cast<ushort4*>(wall)[215040 + which * 32768 + idx] = z;
}

// ---------------------------------------------------------------------------
// MFMA K-loop, BK=64. 128x128 tile, 4 waves x 4x4 frags of 16x16x32 bf16 MFMA.
// lda/ldw = row strides (elements); Kloop = summed K extent.
__device__ __forceinline__ void gemm_seg(const unsigned short* __restrict__ A,
                                         const unsigned short* __restrict__ W,
                                         int m0, int n0, int Kloop, int lda, int ldw,
                                         short* As, short* Bs,
                                         f32x4 (&acc)[4][4], int wave, int lane) {
    const int gi0 = wave * 64 + lane;
    const int gi1 = gi0 + 256;
    const int r0 = gi0 >> 2, c0 = (gi0 & 3) * 8;
    const int r1 = gi1 >> 2, c1 = (gi1 & 3) * 8;

    const unsigned short* pa0 = A + (size_t)(m0 + r0) * lda + c0;
    const unsigned short* pa1 = A + (size_t)(m0 + r1) * lda + c1;
    const unsigned short* pw0 = W + (size_t)(n0 + r0) * ldw + c0;
    const unsigned short* pw1 = W + (size_t)(n0 + r1) * ldw + c1;

    short* ldsA0 = As + wave * 512;
    short* ldsA1 = As + wave * 512 + 2048;
    short* ldsB0 = Bs + wave * 512;
    short* ldsB1 = Bs + wave * 512 + 2048;

    const int wm = wave & 1, wn = wave >> 1;
    const int fr = lane & 15;
    const int fk = (lane >> 4) * 8;

    for (int k0 = 0; k0 < Kloop; k0 += 64) {
#pragma unroll
        for (int t = 0; t < 2; ++t) {
            __builtin_amdgcn_global_load_lds(
                (const __attribute__((address_space(1))) void*)(pa0 + k0 + t * 32),
                (__attribute__((address_space(3))) void*)(ldsA0 + t * 4096), 16, 0, 0);
            __builtin_amdgcn_global_load_lds(
                (const __attribute__((address_space(1))) void*)(pa1 + k0 + t * 32),
                (__attribute__((address_space(3))) void*)(ldsA1 + t * 4096), 16, 0, 0);
            __builtin_amdgcn_global_load_lds(
                (const __attribute__((address_space(1))) void*)(pw0 + k0 + t * 32),
                (__attribute__((address_space(3))) void*)(ldsB0 + t * 4096), 16, 0, 0);
            __builtin_amdgcn_global_load_lds(
                (const __attribute__((address_space(1))) void*)(pw1 + k0 + t * 32),
                (__attribute__((address_space(3))) void*)(ldsB1 + t * 4096), 16, 0, 0);
        }
        __syncthreads();

        bf16x8 af[4][2], bfr[4][2];
#pragma unroll
        for (int i = 0; i < 4; ++i)
#pragma unroll
            for (int t = 0; t < 2; ++t)
                af[i][t] = *reinterpret_cast<const bf16x8*>(
                    &As[t * 4096 + (wm * 64 + i * 16 + fr) * 32 + fk]);
#pragma unroll
        for (int j = 0; j < 4; ++j)
#pragma unroll
            for (int t = 0; t < 2; ++t)
                bfr[j][t] = *reinterpret_cast<const bf16x8*>(
                    &Bs[t * 4096 + (wn * 64 + j * 16 + fr) * 32 + fk]);
#pragma unroll
        for (int i = 0; i < 4; ++i)
#pragma unroll
            for (int j = 0; j < 4; ++j) {
                acc[i][j] = __builtin_amdgcn_mfma_f32_16x16x32_bf16(
                    af[i][0], bfr[j][0], acc[i][j], 0, 0, 0);
                acc[i][j] = __builtin_amdgcn_mfma_f32_16x16x32_bf16(
                    af[i][1], bfr[j][1], acc[i][j], 0, 0, 0);
            }
        __syncthreads();
    }
}

// ---------------------------------------------------------------------------
// Fused input GEMM: cols 0..511 q | 512..1535 kv | 1536..2303 off segs (x3).
// A = x_lo for column tiles >=16 (seg3), x_hi otherwise. grid (18, 64).
__global__ __launch_bounds__(256) void gemm_fused(const unsigned short* __restrict__ x_hi,
                                                  const unsigned short* __restrict__ x_lo,
                                                  const unsigned short* __restrict__ wall,
                                                  const float* __restrict__ bq,
                                                  const float* __restrict__ bkv,
                                                  const float* __restrict__ boff,
                                                  unsigned short* __restrict__ q_bf,
                                                  unsigned short* __restrict__ kv2,
                                                  float* __restrict__ off1,
                                                  float* __restrict__ off2,
                                                  float* __restrict__ off3) {
    __shared__ short As[8192];
    __shared__ short Bs[8192];
    const int t = threadIdx.x;
    const int wave = t >> 6, lane = t & 63;
    const int m0 = blockIdx.y * 128;
    const int n0 = blockIdx.x * 128;

    const unsigned short* A = (blockIdx.x >= 16) ? x_lo : x_hi;

    f32x4 acc[4][4] = {};
    gemm_seg(A, wall, m0, n0, 512, 512, 512, As, Bs, acc, wave, lane);

    const int wm = wave & 1, wn = wave >> 1;
    const int ecol = lane & 15;
    const int erow = (lane >> 4) * 4;
#pragma unroll
    for (int i = 0; i < 4; ++i) {
#pragma unroll
        for (int j = 0; j < 4; ++j) {
            const int n = n0 + wn * 64 + j * 16 + ecol;
#pragma unroll
            for (int r = 0; r < 4; ++r) {
                const int m = m0 + wm * 64 + i * 16 + erow + r;
                const float v = acc[i][j][r];
                if (n < 512) {
                    q_bf[(size_t)m * 512 + n] = f2b((v + bq[n]) * 0.125f);
                } else if (n < 1024) {
                    kv2[(size_t)m * 1024 + 2 * (n - 512)] = f2b(v + bkv[n - 512]);
                } else if (n < 1536) {
                    kv2[(size_t)m * 1024 + 2 * (n - 1024) + 1] = f2b(v + bkv[n - 512]);
                } else if (n < 1792) {
                    const int c = n - 1536;
                    if (c < 144) off1[(size_t)m * 144 + c] = v + boff[c];
                } else if (n < 2048) {
                    const int c = n - 1792;
                    if (c < 144) off2[(size_t)m * 144 + c] = v;
                } else {
                    const int c = n - 2048;
                    if (c < 144) off3[(size_t)m * 144 + c] = v;
                }
            }
        }
    }
}

// ---------------------------------------------------------------------------
// Out-projection GEMM, split-K=2: grid (4, 64, 2). atomicAdd fp32 epilogue
// (d_out zeroed via hipMemsetAsync); bias added by the z==0 half.
__global__ __launch_bounds__(256) void gemm_out(const unsigned short* __restrict__ A,
                                                const unsigned short* __restrict__ W,
                                                const float* __restrict__ bias,
                                                float* __restrict__ out) {
    __shared__ short As[8192];
    __shared__ short Bs[8192];
    const int t = threadIdx.x;
    const int wave = t >> 6, lane = t & 63;
    const int m0 = blockIdx.y * 128;
    const int n0 = blockIdx.x * 128;
    const int kz = blockIdx.z;

    f32x4 acc[4][4] = {};
    gemm_seg(A + kz * 256, W + kz * 256, m0, n0, 256, 512, 512, As, Bs, acc, wave, lane);

    const int wm = wave & 1, wn = wave >> 1;
    const int ecol = lane & 15;
    const int erow = (lane >> 4) * 4;
#pragma unroll
    for (int i = 0; i < 4; ++i) {
#pragma unroll
        for (int j = 0; j < 4; ++j) {
            const int n = n0 + wn * 64 + j * 16 + ecol;
            const float bb = (kz == 0) ? bias[n] : 0.0f;
#pragma unroll
            for (int r = 0; r < 4; ++r) {
                const int m = m0 + wm * 64 + i * 16 + erow + r;
                atomicAdd(&out[(size_t)m * 512 + n], acc[i][j][r] + bb);
            }
        }
    }
}

// ---------------------------------------------------------------------------
// Sampling-parameter precompute: one thread per (b,h,n,p).
// Sums the three offset-GEMM parts, applies tanh*4, emits 4 bilinear weights
// (validity-folded) + 4 clamped kv2 row offsets (ushort units, hh*128 folded).
__global__ __launch_bounds__(256) void samp_prep(const float* __restrict__ off1,
                                                 const float* __restrict__ off2,
                                                 const float* __restrict__ off3,
                                                 float4* __restrict__ sampw,
                                                 int4* __restrict__ sampo) {
    const int pid = blockIdx.x * 256 + threadIdx.x;  // [0, 589824)
    int tmp = pid;
    const int p  = tmp % P_;  tmp /= P_;
    const int n  = tmp & (N_ - 1);
    const int bh = tmp >> 12;
    const int hh = bh & 7;
    const int b  = bh >> 3;

    const size_t tok = (size_t)b * N_ + n;
    const size_t oidx = tok * 144 + hh * 18 + 2 * p;
    const float2 a1 = *reinterpret_cast<const float2*>(off1 + oidx);
    const float2 a2 = *reinterpret_cast<const float2*>(off2 + oidx);
    const float2 a3 = *reinterpret_cast<const float2*>(off3 + oidx);
    const float dx = tanhf(a1.x + a2.x + a3.x) * 4.0f;
    const float dy = tanhf(a1.y + a2.y + a3.y) * 4.0f;
    const float sx = (float)(n & (GW_ - 1)) + dx;
    const float sy = (float)(n >> 8) + dy;
    const float x0f = floorf(sx), y0f = floorf(sy);
    const int x0 = (int)x0f, y0 = (int)y0f;
    const float wx1 = sx - x0f, wy1 = sy - y0f;
    const float wx0 = 1.0f - wx1, wy0 = 1.0f - wy1;

    float4 w;
    int4 ro;
    {
        const int xi = x0, yi = y0;
        const bool v = (xi >= 0) & (xi < GW_) & (yi >= 0) & (yi < GH_);
        w.x = v ? wx0 * wy0 : 0.0f;
        const int xc = xi < 0 ? 0 : (xi > 255 ? 255 : xi);
        const int yc = yi < 0 ? 0 : (yi > 15 ? 15 : yi);
        ro.x = (yc * GW_ + xc) * 1024 + hh * 128;
    }
    {
        const int xi = x0 + 1, yi = y0;
        const bool v = (xi >= 0) & (xi < GW_) & (yi >= 0) & (yi < GH_);
        w.y = v ? wx1 * wy0 : 0.0f;
        const int xc = xi < 0 ? 0 : (xi > 255 ? 255 : xi);
        const int yc = yi < 0 ? 0 : (yi > 15 ? 15 : yi);
        ro.y = (yc * GW_ + xc) * 1024 + hh * 128;
    }
    {
        const int xi = x0, yi = y0 + 1;
        const bool v = (xi >= 0) & (xi < GW_) & (yi >= 0) & (yi < GH_);
        w.z = v ? wx0 * wy1 : 0.0f;
        const int xc = xi < 0 ? 0 : (xi > 255 ? 255 : xi);
        const int yc = yi < 0 ? 0 : (yi > 15 ? 15 : yi);
        ro.z = (yc * GW_ + xc) * 1024 + hh * 128;
    }
    {
        const int xi = x0 + 1, yi = y0 + 1;
        const bool v = (xi >= 0) & (xi < GW_) & (yi >= 0) & (yi < GH_);
        w.w = v ? wx1 * wy1 : 0.0f;
        const int xc = xi < 0 ? 0 : (xi > 255 ? 255 : xi);
        const int yc = yi < 0 ? 0 : (yi > 15 ? 15 : yi);
        ro.w = (yc * GW_ + xc) * 1024 + hh * 128;
    }
    sampw[pid] = w;
    sampo[pid] = ro;
}

// ---------------------------------------------------------------------------
// One wave = 4 consecutive tokens of one (b, head); 16 lanes per token, lane j
// covers channels 4j..4j+3 via one uint4 (bf16 k,v interleaved).
// q_bf pre-scaled by HD^-0.5.
__global__ __launch_bounds__(256) void attn_sample(const unsigned short* __restrict__ q_bf,
                                                   const float4* __restrict__ sampw,
                                                   const int4* __restrict__ sampo,
                                                   const unsigned short* __restrict__ kv2,
                                                   unsigned short* __restrict__ a_bf) {
    const int lane = threadIdx.x & 63;
    const int quarter = lane >> 4;
    const int j    = lane & 15;
    const int wid  = blockIdx.x * 4 + (threadIdx.x >> 6);  // [0, 16384)
    const int b    = wid >> 13;          // H*N/4 = 8192 waves per batch
    const int hh   = (wid >> 10) & 7;    // N/4 = 1024 waves per head
    const int nq   = wid & 1023;
    const int n    = nq * 4 + quarter;

    const size_t tok = (size_t)b * N_ + n;
    const uint2 qp = *reinterpret_cast<const uint2*>(
        q_bf + tok * 512 + hh * 64 + 4 * j);
    const float q0 = b2f_lo(qp.x), q1 = b2f_hi(qp.x);
    const float q2 = b2f_lo(qp.y), q3 = b2f_hi(qp.y);

    const int pbase = ((b * H_ + hh) * N_ + n) * P_;
    const unsigned short* kvbase = kv2 + (size_t)b * (N_ * 1024) + 8 * j;

    float lg[9], s0[9], s1[9], s2[9], s3[9];
    float mx = -1e30f;

#pragma unroll
    for (int p = 0; p < P_; ++p) {
        const float4 w = sampw[pbase + p];
        const int4 ro = sampo[pbase + p];
        float k0 = 0.f, k1 = 0.f, k2 = 0.f, k3 = 0.f;
        float v0 = 0.f, v1 = 0.f, v2 = 0.f, v3 = 0.f;
#pragma unroll
        for (int c = 0; c < 4; ++c) {
            const int r = (c == 0) ? ro.x : (c == 1) ? ro.y : (c == 2) ? ro.z : ro.w;
            const float wgt = (c == 0) ? w.x : (c == 1) ? w.y : (c == 2) ? w.z : w.w;
            const uint4 kv = *reinterpret_cast<const uint4*>(kvbase + r);
            k0 = fmaf(wgt, b2f_lo(kv.x), k0); v0 = fmaf(wgt, b2f_hi(kv.x), v0);
            k1 = fmaf(wgt, b2f_lo(kv.y), k1); v1 = fmaf(wgt, b2f_hi(kv.y), v1);
            k2 = fmaf(wgt, b2f_lo(kv.z), k2); v2 = fmaf(wgt, b2f_hi(kv.z), v2);
            k3 = fmaf(wgt, b2f_lo(kv.w), k3); v3 = fmaf(wgt, b2f_hi(kv.w), v3);
        }
        float ts = fmaf(q0, k0, fmaf(q1, k1, fmaf(q2, k2, q3 * k3)));
#pragma unroll
        for (int s = 8; s > 0; s >>= 1) ts += __shfl_xor(ts, s, 64);  // 16-lane group
        lg[p] = ts;
        s0[p] = v0; s1[p] = v1; s2[p] = v2; s3[p] = v3;
        mx = fmaxf(mx, lg[p]);
    }

    float ssum = 0.f, o0 = 0.f, o1 = 0.f, o2 = 0.f, o3 = 0.f;
#pragma unroll
    for (int p = 0; p < P_; ++p) {
        const float e = __expf(lg[p] - mx);
        ssum += e;
        o0 = fmaf(e, s0[p], o0);
        o1 = fmaf(e, s1[p], o1);
        o2 = fmaf(e, s2[p], o2);
        o3 = fmaf(e, s3[p], o3);
    }
    const float rs = 1.0f / ssum;
    uint2 pack;
    pack.x = (unsigned int)f2b(o0 * rs) | ((unsigned int)f2b(o1 * rs) << 16);
    pack.y = (unsigned int)f2b(o2 * rs) | ((unsigned int)f2b(o3 * rs) << 16);
    *reinterpret_cast<uint2*>(a_bf + tok * 512 + hh * 64 + 4 * j) = pack;
}

// ---------------------------------------------------------------------------
extern "C" void kernel_launch(void* const* d_in, const int* in_sizes, int n_in,
                              void* d_out, int out_size, void* d_ws, size_t ws_size,
                              hipStream_t stream) {
    const float* x    = (const float*)d_in[0];
    const float* bq   = (const float*)d_in[2];
    const float* Woff = (const float*)d_in[3];
    const float* boff = (const float*)d_in[4];
    const float* bkv  = (const float*)d_in[6];
    const float* bo   = (const float*)d_in[8];
    float* out = (float*)d_out;

    // Workspace layout (~77 MB)
    char* ws = (char*)d_ws;
    unsigned short* q_bf    = (unsigned short*)ws; ws += (size_t)M_ * 512 * 2;    // 8 MB
    float*          off1    = (float*)ws;          ws += (size_t)M_ * 144 * 4;    // 4.7 MB
    float*          off2    = (float*)ws;          ws += (size_t)M_ * 144 * 4;    // 4.7 MB
    float*          off3    = (float*)ws;          ws += (size_t)M_ * 144 * 4;    // 4.7 MB
    unsigned short* kv2     = (unsigned short*)ws; ws += (size_t)M_ * 1024 * 2;   // 16.8 MB
    unsigned short* xlo_abf = (unsigned short*)ws; ws += (size_t)M_ * 512 * 2;    // 8 MB (x_lo, then a_bf)
    unsigned short* x_hi    = (unsigned short*)ws; ws += (size_t)M_ * 512 * 2;    // 8 MB
    unsigned short* wall    = (unsigned short*)ws; ws += (size_t)2304 * 512 * 2;  // 2.4 MB
    unsigned short* wob     = (unsigned short*)ws; ws += (size_t)512 * 512 * 2;   // 0.5 MB
    float4*         sampw   = (float4*)ws;         ws += (size_t)M_ * H_ * P_ * 16;  // 9.4 MB
    int4*           sampo   = (int4*)ws;           ws += (size_t)M_ * H_ * P_ * 16;  // 9.4 MB

    const dim3 blk(256);

    // zero d_out for the split-K atomic epilogue (overlaps with early kernels)
    hipMemsetAsync(d_out, 0, (size_t)M_ * 512 * 4, stream);

    // 0) casts (x -> hi/lo, weight wall, wo)
    cast_multi<<<dim3(5360), blk, 0, stream>>>(
        x, (const float*)d_in[1], (const float*)d_in[5], (const float*)d_in[7], Woff,
        x_hi, xlo_abf, wall, wob);

    // 1) fused input GEMM: q + kv + 3 offset segments (N=2304, 1152 blocks)
    gemm_fused<<<dim3(18, M_ / 128), blk, 0, stream>>>(
        x_hi, xlo_abf, wall, bq, bkv, boff, q_bf, kv2, off1, off2, off3);

    // 2) sampling-parameter precompute (sum 3 parts + tanh + bilinear)
    samp_prep<<<dim3(M_ * H_ * P_ / 256), blk, 0, stream>>>(
        off1, off2, off3, sampw, sampo);

    // 3) sampling + attention (4 tokens/wave) -> a_bf (aliases x_lo, now dead)
    attn_sample<<<dim3((B_ * H_ * N_) / 16), blk, 0, stream>>>(
        q_bf, sampw, sampo, kv2, xlo_abf);

    // 4) out = attn @ Wo^T + bo (split-K=2, atomic fp32)
    gemm_out<<<dim3(4, M_ / 128, 2), blk, 0, stream>>>(xlo_abf, wob, bo, out);
}

// Round 8
// 200.298 us; speedup vs baseline: 1.1965x; 1.1065x over previous
//
#include <hip/hip_runtime.h>
#include <hip/hip_bf16.h>

// Problem constants (fixed by the reference module)
static constexpr int B_  = 2;
static constexpr int N_  = 4096;
static constexpr int D_  = 512;
static constexpr int H_  = 8;
static constexpr int P_  = 9;
static constexpr int GH_ = 16;   // grid h
static constexpr int GW_ = 256;  // grid w
static constexpr int M_  = B_ * N_;  // 8192 tokens

typedef __attribute__((ext_vector_type(8))) short bf16x8;
typedef __attribute__((ext_vector_type(4))) float f32x4;

__device__ __forceinline__ unsigned short f2b(float f) {
    __hip_bfloat16 h = __float2bfloat16(f);  // round-to-nearest
    return *reinterpret_cast<unsigned short*>(&h);
}
__device__ __forceinline__ float b2f(unsigned short u) {
    return __uint_as_float(((unsigned int)u) << 16);
}
__device__ __forceinline__ float b2f_lo(unsigned int u) { return __uint_as_float(u << 16); }
__device__ __forceinline__ float b2f_hi(unsigned int u) { return __uint_as_float(u & 0xffff0000u); }

// ---------------------------------------------------------------------------
// Cast fp32 -> bf16 and build the fused weight wall (2304 rows x 512):
//   rows    0..511  Wq | 512..1535 Wkv | 1536..1679 Woff_hi (pad->1791)
//   1792..1935 Woff_lo (pad->2047) | 2048..2191 Woff_hi dup (pad->2303)
__global__ __launch_bounds__(256) void cast_multi(
    const float* __restrict__ x,   const float* __restrict__ wq,
    const float* __restrict__ wkv, const float* __restrict__ wo,
    const float* __restrict__ woff,
    unsigned short* __restrict__ x_hi, unsigned short* __restrict__ x_lo,
    unsigned short* __restrict__ wall, unsigned short* __restrict__ wob) {
    int g = blockIdx.x * 256 + threadIdx.x;

    if (g < 1048576) {  // x -> hi + lo
        float4 v = reinterpret_cast<const float4*>(x)[g];
        ushort4 hi, lo;
        hi.x = f2b(v.x); hi.y = f2b(v.y); hi.z = f2b(v.z); hi.w = f2b(v.w);
        lo.x = f2b(v.x - b2f(hi.x)); lo.y = f2b(v.y - b2f(hi.y));
        lo.z = f2b(v.z - b2f(hi.z)); lo.w = f2b(v.w - b2f(hi.w));
        reinterpret_cast<ushort4*>(x_hi)[g] = hi;
        reinterpret_cast<ushort4*>(x_lo)[g] = lo;
        return;
    }
    g -= 1048576;
    if (g < 65536) {  // Wq -> wall rows 0..511
        float4 v = reinterpret_cast<const float4*>(wq)[g];
        ushort4 o; o.x = f2b(v.x); o.y = f2b(v.y); o.z = f2b(v.z); o.w = f2b(v.w);
        reinterpret_cast<ushort4*>(wall)[g] = o;
        return;
    }
    g -= 65536;
    if (g < 131072) {  // Wkv -> wall rows 512..1535
        float4 v = reinterpret_cast<const float4*>(wkv)[g];
        ushort4 o; o.x = f2b(v.x); o.y = f2b(v.y); o.z = f2b(v.z); o.w = f2b(v.w);
        reinterpret_cast<ushort4*>(wall)[65536 + g] = o;
        return;
    }
    g -= 131072;
    if (g < 65536) {  // Wo -> wob
        float4 v = reinterpret_cast<const float4*>(wo)[g];
        ushort4 o; o.x = f2b(v.x); o.y = f2b(v.y); o.z = f2b(v.z); o.w = f2b(v.w);
        reinterpret_cast<ushort4*>(wob)[g] = o;
        return;
    }
    g -= 65536;
    if (g < 18432) {  // Woff rows 0..143 -> wall hi (1536), lo (1792), hi-dup (2048)
        float4 v = reinterpret_cast<const float4*>(woff)[g];
        ushort4 hi, lo;
        hi.x = f2b(v.x); hi.y = f2b(v.y); hi.z = f2b(v.z); hi.w = f2b(v.w);
        lo.x = f2b(v.x - b2f(hi.x)); lo.y = f2b(v.y - b2f(hi.y));
        lo.z = f2b(v.z - b2f(hi.z)); lo.w = f2b(v.w - b2f(hi.w));
        reinterpret_cast<ushort4*>(wall)[196608 + g] = hi;
        reinterpret_cast<ushort4*>(wall)[229376 + g] = lo;
        reinterpret_cast<ushort4*>(wall)[262144 + g] = hi;
        return;
    }
    g -= 18432;
    // zero pads: rows 1680..1791 / 1936..2047 / 2192..2303 (14336 units each)
    const int which = g / 14336;
    const int idx   = g - which * 14336;
    ushort4 z = {0, 0, 0, 0};
    reinterpret_cast<ushort4*>(wall)[215040 + which * 32768 + idx] = z;
}

// ---------------------------------------------------------------------------
// MFMA K-loop, tile 128(M) x 64(N), BK=32, 12 KB LDS -> high co-residency.
// 4 waves: wm=wave&1 (M half), wn=wave>>1 (N half); wave tile 64x32,
// acc 4x2 f32x4 (32 regs). Staging: A 2 calls + W 1 call of
// global_load_lds width-16 per wave per iter (deposit order == row-major).
__device__ __forceinline__ void gemm_seg(const unsigned short* __restrict__ A,
                                         const unsigned short* __restrict__ W,
                                         int m0, int n0, int Kloop, int lda, int ldw,
                                         short* As, short* Bs,
                                         f32x4 (&acc)[4][2], int wave, int lane) {
    const int gi = wave * 64 + lane;        // [0,256)
    const int r0 = gi >> 2, c0 = (gi & 3) * 8;

    const unsigned short* pa0 = A + (size_t)(m0 + r0) * lda + c0;       // rows 0..63
    const unsigned short* pa1 = A + (size_t)(m0 + 64 + r0) * lda + c0;  // rows 64..127
    const unsigned short* pw  = W + (size_t)(n0 + r0) * ldw + c0;       // rows 0..63

    short* ldsA0 = As + wave * 512;         // call0: shorts [512w, 512w+512)
    short* ldsA1 = As + 2048 + wave * 512;  // call1
    short* ldsB  = Bs + wave * 512;

    const int wm = wave & 1, wn = wave >> 1;
    const int fr = lane & 15;
    const int fk = (lane >> 4) * 8;

    for (int k0 = 0; k0 < Kloop; k0 += 32) {
        __builtin_amdgcn_global_load_lds(
            (const __attribute__((address_space(1))) void*)(pa0 + k0),
            (__attribute__((address_space(3))) void*)ldsA0, 16, 0, 0);
        __builtin_amdgcn_global_load_lds(
            (const __attribute__((address_space(1))) void*)(pa1 + k0),
            (__attribute__((address_space(3))) void*)ldsA1, 16, 0, 0);
        __builtin_amdgcn_global_load_lds(
            (const __attribute__((address_space(1))) void*)(pw + k0),
            (__attribute__((address_space(3))) void*)ldsB, 16, 0, 0);
        __syncthreads();

        bf16x8 af[4], bf[2];
#pragma unroll
        for (int i = 0; i < 4; ++i)
            af[i] = *reinterpret_cast<const bf16x8*>(
                &As[(wm * 64 + i * 16 + fr) * 32 + fk]);
#pragma unroll
        for (int j = 0; j < 2; ++j)
            bf[j] = *reinterpret_cast<const bf16x8*>(
                &Bs[(wn * 32 + j * 16 + fr) * 32 + fk]);
#pragma unroll
        for (int i = 0; i < 4; ++i)
#pragma unroll
            for (int j = 0; j < 2; ++j)
                acc[i][j] = __builtin_amdgcn_mfma_f32_16x16x32_bf16(
                    af[i], bf[j], acc[i][j], 0, 0, 0);
        __syncthreads();
    }
}

// ---------------------------------------------------------------------------
// Fused input GEMM: col tiles (64-wide): 0..7 q | 8..15 k | 16..23 v |
// 24..27 off1(W_hi, x_hi) | 28..31 off2(W_lo, x_hi) | 32..35 off3(W_hi, x_lo).
// grid (36, 64).
__global__ __launch_bounds__(256, 3) void gemm_fused(
    const unsigned short* __restrict__ x_hi,
    const unsigned short* __restrict__ x_lo,
    const unsigned short* __restrict__ wall,
    const float* __restrict__ bq,
    const float* __restrict__ bkv,
    const float* __restrict__ boff,
    unsigned short* __restrict__ q_bf,
    unsigned short* __restrict__ k_bf,
    unsigned short* __restrict__ v_bf,
    float* __restrict__ off1,
    float* __restrict__ off2,
    float* __restrict__ off3) {
    __shared__ short As[4096];  // 128 x 32
    __shared__ short Bs[2048];  // 64 x 32
    const int t = threadIdx.x;
    const int wave = t >> 6, lane = t & 63;
    const int m0 = blockIdx.y * 128;
    const int n0 = blockIdx.x * 64;

    // x_lo pairs with the W_hi-dup segment (n >= 2048), i.e. col tiles 32..35.
    // (R7 bug: selecting 28..31 paired x_lo with W_lo and double-counted
    //  x_hi@W_hi via tiles 32..35 -> garbage offsets.)
    const unsigned short* A = (blockIdx.x >= 32) ? x_lo : x_hi;

    f32x4 acc[4][2] = {};
    gemm_seg(A, wall, m0, n0, 512, 512, 512, As, Bs, acc, wave, lane);

    const int wm = wave & 1, wn = wave >> 1;
    const int ecol = lane & 15;
    const int erow = (lane >> 4) * 4;
#pragma unroll
    for (int i = 0; i < 4; ++i) {
#pragma unroll
        for (int j = 0; j < 2; ++j) {
            const int n = n0 + wn * 32 + j * 16 + ecol;
#pragma unroll
            for (int r = 0; r < 4; ++r) {
                const int m = m0 + wm * 64 + i * 16 + erow + r;
                const float v = acc[i][j][r];
                if (n < 512) {
                    q_bf[(size_t)m * 512 + n] = f2b((v + bq[n]) * 0.125f);
                } else if (n < 1024) {
                    k_bf[(size_t)m * 512 + (n - 512)] = f2b(v + bkv[n - 512]);
                } else if (n < 1536) {
                    v_bf[(size_t)m * 512 + (n - 1024)] = f2b(v + bkv[n - 512]);
                } else if (n < 1792) {
                    const int c = n - 1536;
                    if (c < 144) off1[(size_t)m * 144 + c] = v + boff[c];
                } else if (n < 2048) {
                    const int c = n - 1792;
                    if (c < 144) off2[(size_t)m * 144 + c] = v;
                } else {
                    const int c = n - 2048;
                    if (c < 144) off3[(size_t)m * 144 + c] = v;
                }
            }
        }
    }
}

// ---------------------------------------------------------------------------
// Out-projection GEMM: plain, fp32 store + bias. grid (8, 64).
__global__ __launch_bounds__(256, 3) void gemm_out(
    const unsigned short* __restrict__ A,
    const unsigned short* __restrict__ W,
    const float* __restrict__ bias,
    float* __restrict__ out) {
    __shared__ short As[4096];
    __shared__ short Bs[2048];
    const int t = threadIdx.x;
    const int wave = t >> 6, lane = t & 63;
    const int m0 = blockIdx.y * 128;
    const int n0 = blockIdx.x * 64;

    f32x4 acc[4][2] = {};
    gemm_seg(A, W, m0, n0, 512, 512, 512, As, Bs, acc, wave, lane);

    const int wm = wave & 1, wn = wave >> 1;
    const int ecol = lane & 15;
    const int erow = (lane >> 4) * 4;
#pragma unroll
    for (int i = 0; i < 4; ++i) {
#pragma unroll
        for (int j = 0; j < 2; ++j) {
            const int n = n0 + wn * 32 + j * 16 + ecol;
            const float bb = bias[n];
#pragma unroll
            for (int r = 0; r < 4; ++r) {
                const int m = m0 + wm * 64 + i * 16 + erow + r;
                out[(size_t)m * 512 + n] = acc[i][j][r] + bb;
            }
        }
    }
}

// ---------------------------------------------------------------------------
// Sampling-parameter precompute: one thread per (b,h,n,p).
// Sums the three offset-GEMM parts, tanh*4, emits 4 validity-folded bilinear
// weights + 4 clamped row offsets (ushort units into the 512-stride k/v
// planes, hh*64 folded in).
__global__ __launch_bounds__(256) void samp_prep(const float* __restrict__ off1,
                                                 const float* __restrict__ off2,
                                                 const float* __restrict__ off3,
                                                 float4* __restrict__ sampw,
                                                 int4* __restrict__ sampo) {
    const int pid = blockIdx.x * 256 + threadIdx.x;  // [0, 589824)
    int tmp = pid;
    const int p  = tmp % P_;  tmp /= P_;
    const int n  = tmp & (N_ - 1);
    const int bh = tmp >> 12;
    const int hh = bh & 7;
    const int b  = bh >> 3;

    const size_t tok = (size_t)b * N_ + n;
    const size_t oidx = tok * 144 + hh * 18 + 2 * p;
    const float2 a1 = *reinterpret_cast<const float2*>(off1 + oidx);
    const float2 a2 = *reinterpret_cast<const float2*>(off2 + oidx);
    const float2 a3 = *reinterpret_cast<const float2*>(off3 + oidx);
    const float dx = tanhf(a1.x + a2.x + a3.x) * 4.0f;
    const float dy = tanhf(a1.y + a2.y + a3.y) * 4.0f;
    const float sx = (float)(n & (GW_ - 1)) + dx;
    const float sy = (float)(n >> 8) + dy;
    const float x0f = floorf(sx), y0f = floorf(sy);
    const int x0 = (int)x0f, y0 = (int)y0f;
    const float wx1 = sx - x0f, wy1 = sy - y0f;
    const float wx0 = 1.0f - wx1, wy0 = 1.0f - wy1;

    float4 w;
    int4 ro;
    {
        const int xi = x0, yi = y0;
        const bool v = (xi >= 0) & (xi < GW_) & (yi >= 0) & (yi < GH_);
        w.x = v ? wx0 * wy0 : 0.0f;
        const int xc = xi < 0 ? 0 : (xi > 255 ? 255 : xi);
        const int yc = yi < 0 ? 0 : (yi > 15 ? 15 : yi);
        ro.x = (yc * GW_ + xc) * 512 + hh * 64;
    }
    {
        const int xi = x0 + 1, yi = y0;
        const bool v = (xi >= 0) & (xi < GW_) & (yi >= 0) & (yi < GH_);
        w.y = v ? wx1 * wy0 : 0.0f;
        const int xc = xi < 0 ? 0 : (xi > 255 ? 255 : xi);
        const int yc = yi < 0 ? 0 : (yi > 15 ? 15 : yi);
        ro.y = (yc * GW_ + xc) * 512 + hh * 64;
    }
    {
        const int xi = x0, yi = y0 + 1;
        const bool v = (xi >= 0) & (xi < GW_) & (yi >= 0) & (yi < GH_);
        w.z = v ? wx0 * wy1 : 0.0f;
        const int xc = xi < 0 ? 0 : (xi > 255 ? 255 : xi);
        const int yc = yi < 0 ? 0 : (yi > 15 ? 15 : yi);
        ro.z = (yc * GW_ + xc) * 512 + hh * 64;
    }
    {
        const int xi = x0 + 1, yi = y0 + 1;
        const bool v = (xi >= 0) & (xi < GW_) & (yi >= 0) & (yi < GH_);
        w.w = v ? wx1 * wy1 : 0.0f;
        const int xc = xi < 0 ? 0 : (xi > 255 ? 255 : xi);
        const int yc = yi < 0 ? 0 : (yi > 15 ? 15 : yi);
        ro.w = (yc * GW_ + xc) * 512 + hh * 64;
    }
    sampw[pid] = w;
    sampo[pid] = ro;
}

// ---------------------------------------------------------------------------
// One wave = 4 consecutive tokens of one (b, head); 16 lanes per token, lane j
// covers channels 4j..4j+3 via one uint2 from each of the k and v planes.
// q_bf pre-scaled by HD^-0.5.
__global__ __launch_bounds__(256) void attn_sample(const unsigned short* __restrict__ q_bf,
                                                   const float4* __restrict__ sampw,
                                                   const int4* __restrict__ sampo,
                                                   const unsigned short* __restrict__ k_bf,
                                                   const unsigned short* __restrict__ v_bf,
                                                   unsigned short* __restrict__ a_bf) {
    const int lane = threadIdx.x & 63;
    const int quarter = lane >> 4;
    const int j    = lane & 15;
    const int wid  = blockIdx.x * 4 + (threadIdx.x >> 6);  // [0, 16384)
    const int b    = wid >> 13;
    const int hh   = (wid >> 10) & 7;
    const int nq   = wid & 1023;
    const int n    = nq * 4 + quarter;

    const size_t tok = (size_t)b * N_ + n;
    const uint2 qp = *reinterpret_cast<const uint2*>(
        q_bf + tok * 512 + hh * 64 + 4 * j);
    const float q0 = b2f_lo(qp.x), q1 = b2f_hi(qp.x);
    const float q2 = b2f_lo(qp.y), q3 = b2f_hi(qp.y);

    const int pbase = ((b * H_ + hh) * N_ + n) * P_;
    const unsigned short* kbase = k_bf + (size_t)b * (N_ * 512) + 4 * j;
    const unsigned short* vbase = v_bf + (size_t)b * (N_ * 512) + 4 * j;

    float lg[9], s0[9], s1[9], s2[9], s3[9];
    float mx = -1e30f;

#pragma unroll
    for (int p = 0; p < P_; ++p) {
        const float4 w = sampw[pbase + p];
        const int4 ro = sampo[pbase + p];
        float k0 = 0.f, k1 = 0.f, k2 = 0.f, k3 = 0.f;
        float v0 = 0.f, v1 = 0.f, v2 = 0.f, v3 = 0.f;
#pragma unroll
        for (int c = 0; c < 4; ++c) {
            const int r = (c == 0) ? ro.x : (c == 1) ? ro.y : (c == 2) ? ro.z : ro.w;
            const float wgt = (c == 0) ? w.x : (c == 1) ? w.y : (c == 2) ? w.z : w.w;
            const uint2 ku = *reinterpret_cast<const uint2*>(kbase + r);
            const uint2 vu = *reinterpret_cast<const uint2*>(vbase + r);
            k0 = fmaf(wgt, b2f_lo(ku.x), k0); k1 = fmaf(wgt, b2f_hi(ku.x), k1);
            k2 = fmaf(wgt, b2f_lo(ku.y), k2); k3 = fmaf(wgt, b2f_hi(ku.y), k3);
            v0 = fmaf(wgt, b2f_lo(vu.x), v0); v1 = fmaf(wgt, b2f_hi(vu.x), v1);
            v2 = fmaf(wgt, b2f_lo(vu.y), v2); v3 = fmaf(wgt, b2f_hi(vu.y), v3);
        }
        float ts = fmaf(q0, k0, fmaf(q1, k1, fmaf(q2, k2, q3 * k3)));
#pragma unroll
        for (int s = 8; s > 0; s >>= 1) ts += __shfl_xor(ts, s, 64);  // 16-lane group
        lg[p] = ts;
        s0[p] = v0; s1[p] = v1; s2[p] = v2; s3[p] = v3;
        mx = fmaxf(mx, lg[p]);
    }

    float ssum = 0.f, o0 = 0.f, o1 = 0.f, o2 = 0.f, o3 = 0.f;
#pragma unroll
    for (int p = 0; p < P_; ++p) {
        const float e = __expf(lg[p] - mx);
        ssum += e;
        o0 = fmaf(e, s0[p], o0);
        o1 = fmaf(e, s1[p], o1);
        o2 = fmaf(e, s2[p], o2);
        o3 = fmaf(e, s3[p], o3);
    }
    const float rs = 1.0f / ssum;
    uint2 pack;
    pack.x = (unsigned int)f2b(o0 * rs) | ((unsigned int)f2b(o1 * rs) << 16);
    pack.y = (unsigned int)f2b(o2 * rs) | ((unsigned int)f2b(o3 * rs) << 16);
    *reinterpret_cast<uint2*>(a_bf + tok * 512 + hh * 64 + 4 * j) = pack;
}

// ---------------------------------------------------------------------------
extern "C" void kernel_launch(void* const* d_in, const int* in_sizes, int n_in,
                              void* d_out, int out_size, void* d_ws, size_t ws_size,
                              hipStream_t stream) {
    const float* x    = (const float*)d_in[0];
    const float* bq   = (const float*)d_in[2];
    const float* Woff = (const float*)d_in[3];
    const float* boff = (const float*)d_in[4];
    const float* bkv  = (const float*)d_in[6];
    const float* bo   = (const float*)d_in[8];
    float* out = (float*)d_out;

    // Workspace layout (~76 MB)
    char* ws = (char*)d_ws;
    unsigned short* q_bf    = (unsigned short*)ws; ws += (size_t)M_ * 512 * 2;    // 8 MB
    unsigned short* k_bf    = (unsigned short*)ws; ws += (size_t)M_ * 512 * 2;    // 8 MB
    unsigned short* v_bf    = (unsigned short*)ws; ws += (size_t)M_ * 512 * 2;    // 8 MB
    float*          off1    = (float*)ws;          ws += (size_t)M_ * 144 * 4;    // 4.7 MB
    float*          off2    = (float*)ws;          ws += (size_t)M_ * 144 * 4;    // 4.7 MB
    float*          off3    = (float*)ws;          ws += (size_t)M_ * 144 * 4;    // 4.7 MB
    unsigned short* xlo_abf = (unsigned short*)ws; ws += (size_t)M_ * 512 * 2;    // 8 MB (x_lo, then a_bf)
    unsigned short* x_hi    = (unsigned short*)ws; ws += (size_t)M_ * 512 * 2;    // 8 MB
    unsigned short* wall    = (unsigned short*)ws; ws += (size_t)2304 * 512 * 2;  // 2.4 MB
    unsigned short* wob     = (unsigned short*)ws; ws += (size_t)512 * 512 * 2;   // 0.5 MB
    float4*         sampw   = (float4*)ws;         ws += (size_t)M_ * H_ * P_ * 16;  // 9.4 MB
    int4*           sampo   = (int4*)ws;           ws += (size_t)M_ * H_ * P_ * 16;  // 9.4 MB

    const dim3 blk(256);

    // 0) casts (x -> hi/lo, weight wall, wo)
    cast_multi<<<dim3(5360), blk, 0, stream>>>(
        x, (const float*)d_in[1], (const float*)d_in[5], (const float*)d_in[7], Woff,
        x_hi, xlo_abf, wall, wob);

    // 1) fused input GEMM: q + k + v + 3 offset segments (2304 blocks)
    gemm_fused<<<dim3(36, M_ / 128), blk, 0, stream>>>(
        x_hi, xlo_abf, wall, bq, bkv, boff, q_bf, k_bf, v_bf, off1, off2, off3);

    // 2) sampling-parameter precompute (sum 3 parts + tanh + bilinear)
    samp_prep<<<dim3(M_ * H_ * P_ / 256), blk, 0, stream>>>(
        off1, off2, off3, sampw, sampo);

    // 3) sampling + attention (4 tokens/wave) -> a_bf (aliases x_lo, now dead)
    attn_sample<<<dim3((B_ * H_ * N_) / 16), blk, 0, stream>>>(
        q_bf, sampw, sampo, k_bf, v_bf, xlo_abf);

    // 4) out = attn @ Wo^T + bo (plain fp32 store)
    gemm_out<<<dim3(8, M_ / 128), blk, 0, stream>>>(xlo_abf, wob, bo, out);
}

// Round 9
// 180.463 us; speedup vs baseline: 1.3280x; 1.1099x over previous
//
#include <hip/hip_runtime.h>
#include <hip/hip_bf16.h>

// Problem constants (fixed by the reference module)
static constexpr int B_  = 2;
static constexpr int N_  = 4096;
static constexpr int D_  = 512;
static constexpr int H_  = 8;
static constexpr int P_  = 9;
static constexpr int GH_ = 16;   // grid h
static constexpr int GW_ = 256;  // grid w
static constexpr int M_  = B_ * N_;  // 8192 tokens

typedef __attribute__((ext_vector_type(8))) short bf16x8;
typedef __attribute__((ext_vector_type(4))) float f32x4;

__device__ __forceinline__ unsigned short f2b(float f) {
    __hip_bfloat16 h = __float2bfloat16(f);  // round-to-nearest
    return *reinterpret_cast<unsigned short*>(&h);
}
__device__ __forceinline__ float b2f(unsigned short u) {
    return __uint_as_float(((unsigned int)u) << 16);
}
__device__ __forceinline__ float b2f_lo(unsigned int u) { return __uint_as_float(u << 16); }
__device__ __forceinline__ float b2f_hi(unsigned int u) { return __uint_as_float(u & 0xffff0000u); }

// ---------------------------------------------------------------------------
// Cast fp32 -> bf16 and build the fused weight wall (2304 rows x 512):
//   rows    0..511  Wq | 512..1535 Wkv | 1536..1679 Woff_hi (pad->1791)
//   1792..1935 Woff_lo (pad->2047) | 2048..2191 Woff_hi dup (pad->2303)
__global__ __launch_bounds__(256) void cast_multi(
    const float* __restrict__ x,   const float* __restrict__ wq,
    const float* __restrict__ wkv, const float* __restrict__ wo,
    const float* __restrict__ woff,
    unsigned short* __restrict__ x_hi, unsigned short* __restrict__ x_lo,
    unsigned short* __restrict__ wall, unsigned short* __restrict__ wob) {
    int g = blockIdx.x * 256 + threadIdx.x;

    if (g < 1048576) {  // x -> hi + lo
        float4 v = reinterpret_cast<const float4*>(x)[g];
        ushort4 hi, lo;
        hi.x = f2b(v.x); hi.y = f2b(v.y); hi.z = f2b(v.z); hi.w = f2b(v.w);
        lo.x = f2b(v.x - b2f(hi.x)); lo.y = f2b(v.y - b2f(hi.y));
        lo.z = f2b(v.z - b2f(hi.z)); lo.w = f2b(v.w - b2f(hi.w));
        reinterpret_cast<ushort4*>(x_hi)[g] = hi;
        reinterpret_cast<ushort4*>(x_lo)[g] = lo;
        return;
    }
    g -= 1048576;
    if (g < 65536) {  // Wq -> wall rows 0..511
        float4 v = reinterpret_cast<const float4*>(wq)[g];
        ushort4 o; o.x = f2b(v.x); o.y = f2b(v.y); o.z = f2b(v.z); o.w = f2b(v.w);
        reinterpret_cast<ushort4*>(wall)[g] = o;
        return;
    }
    g -= 65536;
    if (g < 131072) {  // Wkv -> wall rows 512..1535
        float4 v = reinterpret_cast<const float4*>(wkv)[g];
        ushort4 o; o.x = f2b(v.x); o.y = f2b(v.y); o.z = f2b(v.z); o.w = f2b(v.w);
        reinterpret_cast<ushort4*>(wall)[65536 + g] = o;
        return;
    }
    g -= 131072;
    if (g < 65536) {  // Wo -> wob
        float4 v = reinterpret_cast<const float4*>(wo)[g];
        ushort4 o; o.x = f2b(v.x); o.y = f2b(v.y); o.z = f2b(v.z); o.w = f2b(v.w);
        reinterpret_cast<ushort4*>(wob)[g] = o;
        return;
    }
    g -= 65536;
    if (g < 18432) {  // Woff rows 0..143 -> wall hi (1536), lo (1792), hi-dup (2048)
        float4 v = reinterpret_cast<const float4*>(woff)[g];
        ushort4 hi, lo;
        hi.x = f2b(v.x); hi.y = f2b(v.y); hi.z = f2b(v.z); hi.w = f2b(v.w);
        lo.x = f2b(v.x - b2f(hi.x)); lo.y = f2b(v.y - b2f(hi.y));
        lo.z = f2b(v.z - b2f(hi.z)); lo.w = f2b(v.w - b2f(hi.w));
        reinterpret_cast<ushort4*>(wall)[196608 + g] = hi;
        reinterpret_cast<ushort4*>(wall)[229376 + g] = lo;
        reinterpret_cast<ushort4*>(wall)[262144 + g] = hi;
        return;
    }
    g -= 18432;
    // zero pads: rows 1680..1791 / 1936..2047 / 2192..2303 (14336 units each)
    const int which = g / 14336;
    const int idx   = g - which * 14336;
    ushort4 z = {0, 0, 0, 0};
    reinterpret_cast<ushort4*>(wall)[215040 + which * 32768 + idx] = z;
}

// ---------------------------------------------------------------------------
// MFMA K-loop, tile 128(M) x 64(N), BK=64 (two 32-chunks per barrier pair ->
// 16 MFMA/wave/iter), LDS 24 KB. 4 waves: wm=wave&1, wn=wave>>1.
// Chunk t: A at As + t*4096 shorts (row-major [128][32]), B at Bs + t*2048.
// Fragments consumed chunk-at-a-time to cap live registers.
__device__ __forceinline__ void gemm_seg(const unsigned short* __restrict__ A,
                                         const unsigned short* __restrict__ W,
                                         int m0, int n0, int Kloop, int lda, int ldw,
                                         short* As, short* Bs,
                                         f32x4 (&acc)[4][2], int wave, int lane) {
    const int gi = wave * 64 + lane;        // [0,256)
    const int r0 = gi >> 2, c0 = (gi & 3) * 8;

    const unsigned short* pa0 = A + (size_t)(m0 + r0) * lda + c0;       // rows 0..63
    const unsigned short* pa1 = A + (size_t)(m0 + 64 + r0) * lda + c0;  // rows 64..127
    const unsigned short* pw  = W + (size_t)(n0 + r0) * ldw + c0;       // rows 0..63

    const int wm = wave & 1, wn = wave >> 1;
    const int fr = lane & 15;
    const int fk = (lane >> 4) * 8;

    for (int k0 = 0; k0 < Kloop; k0 += 64) {
#pragma unroll
        for (int t = 0; t < 2; ++t) {
            __builtin_amdgcn_global_load_lds(
                (const __attribute__((address_space(1))) void*)(pa0 + k0 + t * 32),
                (__attribute__((address_space(3))) void*)(As + t * 4096 + wave * 512),
                16, 0, 0);
            __builtin_amdgcn_global_load_lds(
                (const __attribute__((address_space(1))) void*)(pa1 + k0 + t * 32),
                (__attribute__((address_space(3))) void*)(As + t * 4096 + 2048 + wave * 512),
                16, 0, 0);
            __builtin_amdgcn_global_load_lds(
                (const __attribute__((address_space(1))) void*)(pw + k0 + t * 32),
                (__attribute__((address_space(3))) void*)(Bs + t * 2048 + wave * 512),
                16, 0, 0);
        }
        __syncthreads();

#pragma unroll
        for (int t = 0; t < 2; ++t) {
            bf16x8 af[4], bf[2];
#pragma unroll
            for (int i = 0; i < 4; ++i)
                af[i] = *reinterpret_cast<const bf16x8*>(
                    &As[t * 4096 + (wm * 64 + i * 16 + fr) * 32 + fk]);
#pragma unroll
            for (int j = 0; j < 2; ++j)
                bf[j] = *reinterpret_cast<const bf16x8*>(
                    &Bs[t * 2048 + (wn * 32 + j * 16 + fr) * 32 + fk]);
#pragma unroll
            for (int i = 0; i < 4; ++i)
#pragma unroll
                for (int j = 0; j < 2; ++j)
                    acc[i][j] = __builtin_amdgcn_mfma_f32_16x16x32_bf16(
                        af[i], bf[j], acc[i][j], 0, 0, 0);
        }
        __syncthreads();
    }
}

// ---------------------------------------------------------------------------
// Fused input GEMM: col tiles (64-wide): 0..7 q | 8..15 k | 16..23 v |
// 24..27 off1(W_hi, x_hi) | 28..31 off2(W_lo, x_hi) | 32..35 off3(W_hi, x_lo).
// grid (36, 64).
__global__ __launch_bounds__(256, 3) void gemm_fused(
    const unsigned short* __restrict__ x_hi,
    const unsigned short* __restrict__ x_lo,
    const unsigned short* __restrict__ wall,
    const float* __restrict__ bq,
    const float* __restrict__ bkv,
    const float* __restrict__ boff,
    unsigned short* __restrict__ q_bf,
    unsigned short* __restrict__ k_bf,
    unsigned short* __restrict__ v_bf,
    float* __restrict__ off1,
    float* __restrict__ off2,
    float* __restrict__ off3) {
    __shared__ short As[8192];  // 2 chunks x [128][32]
    __shared__ short Bs[4096];  // 2 chunks x [64][32]
    const int t = threadIdx.x;
    const int wave = t >> 6, lane = t & 63;
    const int m0 = blockIdx.y * 128;
    const int n0 = blockIdx.x * 64;

    // x_lo pairs with the W_hi-dup segment (n >= 2048), i.e. col tiles 32..35.
    const unsigned short* A = (blockIdx.x >= 32) ? x_lo : x_hi;

    f32x4 acc[4][2] = {};
    gemm_seg(A, wall, m0, n0, 512, 512, 512, As, Bs, acc, wave, lane);

    const int wm = wave & 1, wn = wave >> 1;
    const int ecol = lane & 15;
    const int erow = (lane >> 4) * 4;
#pragma unroll
    for (int i = 0; i < 4; ++i) {
#pragma unroll
        for (int j = 0; j < 2; ++j) {
            const int n = n0 + wn * 32 + j * 16 + ecol;
#pragma unroll
            for (int r = 0; r < 4; ++r) {
                const int m = m0 + wm * 64 + i * 16 + erow + r;
                const float v = acc[i][j][r];
                if (n < 512) {
                    q_bf[(size_t)m * 512 + n] = f2b((v + bq[n]) * 0.125f);
                } else if (n < 1024) {
                    k_bf[(size_t)m * 512 + (n - 512)] = f2b(v + bkv[n - 512]);
                } else if (n < 1536) {
                    v_bf[(size_t)m * 512 + (n - 1024)] = f2b(v + bkv[n - 512]);
                } else if (n < 1792) {
                    const int c = n - 1536;
                    if (c < 144) off1[(size_t)m * 144 + c] = v + boff[c];
                } else if (n < 2048) {
                    const int c = n - 1792;
                    if (c < 144) off2[(size_t)m * 144 + c] = v;
                } else {
                    const int c = n - 2048;
                    if (c < 144) off3[(size_t)m * 144 + c] = v;
                }
            }
        }
    }
}

// ---------------------------------------------------------------------------
// Out-projection GEMM: plain, fp32 store + bias. grid (8, 64).
__global__ __launch_bounds__(256, 3) void gemm_out(
    const unsigned short* __restrict__ A,
    const unsigned short* __restrict__ W,
    const float* __restrict__ bias,
    float* __restrict__ out) {
    __shared__ short As[8192];
    __shared__ short Bs[4096];
    const int t = threadIdx.x;
    const int wave = t >> 6, lane = t & 63;
    const int m0 = blockIdx.y * 128;
    const int n0 = blockIdx.x * 64;

    f32x4 acc[4][2] = {};
    gemm_seg(A, W, m0, n0, 512, 512, 512, As, Bs, acc, wave, lane);

    const int wm = wave & 1, wn = wave >> 1;
    const int ecol = lane & 15;
    const int erow = (lane >> 4) * 4;
#pragma unroll
    for (int i = 0; i < 4; ++i) {
#pragma unroll
        for (int j = 0; j < 2; ++j) {
            const int n = n0 + wn * 32 + j * 16 + ecol;
            const float bb = bias[n];
#pragma unroll
            for (int r = 0; r < 4; ++r) {
                const int m = m0 + wm * 64 + i * 16 + erow + r;
                out[(size_t)m * 512 + n] = acc[i][j][r] + bb;
            }
        }
    }
}

// ---------------------------------------------------------------------------
// Sampling + attention, with inlined parameter computation (samp_prep fused).
// One wave = 4 consecutive tokens of one (b, head); 16 lanes per token, lane j
// covers channels 4j..4j+3 via one uint2 from each of the k and v planes.
// Lanes 0..35 first compute the wave's 4x9 sampling params (sum 3 offset-GEMM
// parts, tanh*4, bilinear weights + clamped row offsets) into LDS.
__global__ __launch_bounds__(256) void attn_sample(const unsigned short* __restrict__ q_bf,
                                                   const float* __restrict__ off1,
                                                   const float* __restrict__ off2,
                                                   const float* __restrict__ off3,
                                                   const unsigned short* __restrict__ k_bf,
                                                   const unsigned short* __restrict__ v_bf,
                                                   unsigned short* __restrict__ a_bf) {
    __shared__ float4 pw_s[4][36];
    __shared__ int4   po_s[4][36];

    const int lane = threadIdx.x & 63;
    const int wave = threadIdx.x >> 6;
    const int quarter = lane >> 4;
    const int j    = lane & 15;
    const int wid  = blockIdx.x * 4 + wave;  // [0, 16384)
    const int b    = wid >> 13;
    const int hh   = (wid >> 10) & 7;
    const int nq   = wid & 1023;
    const int n    = nq * 4 + quarter;

    // ---- parameter computation: lane l < 36 handles (qt = l/9, p = l%9) ----
    if (lane < 36) {
        const int qt = lane / 9;
        const int p  = lane - qt * 9;
        const int tn = nq * 4 + qt;
        const size_t tokq = (size_t)b * N_ + tn;
        const size_t oidx = tokq * 144 + hh * 18 + 2 * p;
        const float2 a1 = *reinterpret_cast<const float2*>(off1 + oidx);
        const float2 a2 = *reinterpret_cast<const float2*>(off2 + oidx);
        const float2 a3 = *reinterpret_cast<const float2*>(off3 + oidx);
        const float dx = tanhf(a1.x + a2.x + a3.x) * 4.0f;
        const float dy = tanhf(a1.y + a2.y + a3.y) * 4.0f;
        const float sx = (float)(tn & (GW_ - 1)) + dx;
        const float sy = (float)(tn >> 8) + dy;
        const float x0f = floorf(sx), y0f = floorf(sy);
        const int x0 = (int)x0f, y0 = (int)y0f;
        const float wx1 = sx - x0f, wy1 = sy - y0f;
        const float wx0 = 1.0f - wx1, wy0 = 1.0f - wy1;

        float4 w;
        int4 ro;
        {
            const int xi = x0, yi = y0;
            const bool v = (xi >= 0) & (xi < GW_) & (yi >= 0) & (yi < GH_);
            w.x = v ? wx0 * wy0 : 0.0f;
            const int xc = xi < 0 ? 0 : (xi > 255 ? 255 : xi);
            const int yc = yi < 0 ? 0 : (yi > 15 ? 15 : yi);
            ro.x = (yc * GW_ + xc) * 512 + hh * 64;
        }
        {
            const int xi = x0 + 1, yi = y0;
            const bool v = (xi >= 0) & (xi < GW_) & (yi >= 0) & (yi < GH_);
            w.y = v ? wx1 * wy0 : 0.0f;
            const int xc = xi < 0 ? 0 : (xi > 255 ? 255 : xi);
            const int yc = yi < 0 ? 0 : (yi > 15 ? 15 : yi);
            ro.y = (yc * GW_ + xc) * 512 + hh * 64;
        }
        {
            const int xi = x0, yi = y0 + 1;
            const bool v = (xi >= 0) & (xi < GW_) & (yi >= 0) & (yi < GH_);
            w.z = v ? wx0 * wy1 : 0.0f;
            const int xc = xi < 0 ? 0 : (xi > 255 ? 255 : xi);
            const int yc = yi < 0 ? 0 : (yi > 15 ? 15 : yi);
            ro.z = (yc * GW_ + xc) * 512 + hh * 64;
        }
        {
            const int xi = x0 + 1, yi = y0 + 1;
            const bool v = (xi >= 0) & (xi < GW_) & (yi >= 0) & (yi < GH_);
            w.w = v ? wx1 * wy1 : 0.0f;
            const int xc = xi < 0 ? 0 : (xi > 255 ? 255 : xi);
            const int yc = yi < 0 ? 0 : (yi > 15 ? 15 : yi);
            ro.w = (yc * GW_ + xc) * 512 + hh * 64;
        }
        pw_s[wave][lane] = w;
        po_s[wave][lane] = ro;
    }
    __syncthreads();

    // ---- sampling + attention ----
    const size_t tok = (size_t)b * N_ + n;
    const uint2 qp = *reinterpret_cast<const uint2*>(
        q_bf + tok * 512 + hh * 64 + 4 * j);
    const float q0 = b2f_lo(qp.x), q1 = b2f_hi(qp.x);
    const float q2 = b2f_lo(qp.y), q3 = b2f_hi(qp.y);

    const unsigned short* kbase = k_bf + (size_t)b * (N_ * 512) + 4 * j;
    const unsigned short* vbase = v_bf + (size_t)b * (N_ * 512) + 4 * j;
    const int ebase = quarter * 9;

    float lg[9], s0[9], s1[9], s2[9], s3[9];
    float mx = -1e30f;

#pragma unroll
    for (int p = 0; p < P_; ++p) {
        const float4 w = pw_s[wave][ebase + p];
        const int4 ro = po_s[wave][ebase + p];
        float k0 = 0.f, k1 = 0.f, k2 = 0.f, k3 = 0.f;
        float v0 = 0.f, v1 = 0.f, v2 = 0.f, v3 = 0.f;
#pragma unroll
        for (int c = 0; c < 4; ++c) {
            const int r = (c == 0) ? ro.x : (c == 1) ? ro.y : (c == 2) ? ro.z : ro.w;
            const float wgt = (c == 0) ? w.x : (c == 1) ? w.y : (c == 2) ? w.z : w.w;
            const uint2 ku = *reinterpret_cast<const uint2*>(kbase + r);
            const uint2 vu = *reinterpret_cast<const uint2*>(vbase + r);
            k0 = fmaf(wgt, b2f_lo(ku.x), k0); k1 = fmaf(wgt, b2f_hi(ku.x), k1);
            k2 = fmaf(wgt, b2f_lo(ku.y), k2); k3 = fmaf(wgt, b2f_hi(ku.y), k3);
            v0 = fmaf(wgt, b2f_lo(vu.x), v0); v1 = fmaf(wgt, b2f_hi(vu.x), v1);
            v2 = fmaf(wgt, b2f_lo(vu.y), v2); v3 = fmaf(wgt, b2f_hi(vu.y), v3);
        }
        float ts = fmaf(q0, k0, fmaf(q1, k1, fmaf(q2, k2, q3 * k3)));
#pragma unroll
        for (int s = 8; s > 0; s >>= 1) ts += __shfl_xor(ts, s, 64);  // 16-lane group
        lg[p] = ts;
        s0[p] = v0; s1[p] = v1; s2[p] = v2; s3[p] = v3;
        mx = fmaxf(mx, lg[p]);
    }

    float ssum = 0.f, o0 = 0.f, o1 = 0.f, o2 = 0.f, o3 = 0.f;
#pragma unroll
    for (int p = 0; p < P_; ++p) {
        const float e = __expf(lg[p] - mx);
        ssum += e;
        o0 = fmaf(e, s0[p], o0);
        o1 = fmaf(e, s1[p], o1);
        o2 = fmaf(e, s2[p], o2);
        o3 = fmaf(e, s3[p], o3);
    }
    const float rs = 1.0f / ssum;
    uint2 pack;
    pack.x = (unsigned int)f2b(o0 * rs) | ((unsigned int)f2b(o1 * rs) << 16);
    pack.y = (unsigned int)f2b(o2 * rs) | ((unsigned int)f2b(o3 * rs) << 16);
    *reinterpret_cast<uint2*>(a_bf + tok * 512 + hh * 64 + 4 * j) = pack;
}

// ---------------------------------------------------------------------------
extern "C" void kernel_launch(void* const* d_in, const int* in_sizes, int n_in,
                              void* d_out, int out_size, void* d_ws, size_t ws_size,
                              hipStream_t stream) {
    const float* x    = (const float*)d_in[0];
    const float* bq   = (const float*)d_in[2];
    const float* Woff = (const float*)d_in[3];
    const float* boff = (const float*)d_in[4];
    const float* bkv  = (const float*)d_in[6];
    const float* bo   = (const float*)d_in[8];
    float* out = (float*)d_out;

    // Workspace layout (~57 MB)
    char* ws = (char*)d_ws;
    unsigned short* q_bf    = (unsigned short*)ws; ws += (size_t)M_ * 512 * 2;    // 8 MB
    unsigned short* k_bf    = (unsigned short*)ws; ws += (size_t)M_ * 512 * 2;    // 8 MB
    unsigned short* v_bf    = (unsigned short*)ws; ws += (size_t)M_ * 512 * 2;    // 8 MB
    float*          off1    = (float*)ws;          ws += (size_t)M_ * 144 * 4;    // 4.7 MB
    float*          off2    = (float*)ws;          ws += (size_t)M_ * 144 * 4;    // 4.7 MB
    float*          off3    = (float*)ws;          ws += (size_t)M_ * 144 * 4;    // 4.7 MB
    unsigned short* xlo_abf = (unsigned short*)ws; ws += (size_t)M_ * 512 * 2;    // 8 MB (x_lo, then a_bf)
    unsigned short* x_hi    = (unsigned short*)ws; ws += (size_t)M_ * 512 * 2;    // 8 MB
    unsigned short* wall    = (unsigned short*)ws; ws += (size_t)2304 * 512 * 2;  // 2.4 MB
    unsigned short* wob     = (unsigned short*)ws; ws += (size_t)512 * 512 * 2;   // 0.5 MB

    const dim3 blk(256);

    // 0) casts (x -> hi/lo, weight wall, wo)
    cast_multi<<<dim3(5360), blk, 0, stream>>>(
        x, (const float*)d_in[1], (const float*)d_in[5], (const float*)d_in[7], Woff,
        x_hi, xlo_abf, wall, wob);

    // 1) fused input GEMM: q + k + v + 3 offset segments (2304 blocks)
    gemm_fused<<<dim3(36, M_ / 128), blk, 0, stream>>>(
        x_hi, xlo_abf, wall, bq, bkv, boff, q_bf, k_bf, v_bf, off1, off2, off3);

    // 2) sampling + attention with fused param prep -> a_bf (aliases x_lo)
    attn_sample<<<dim3((B_ * H_ * N_) / 16), blk, 0, stream>>>(
        q_bf, off1, off2, off3, k_bf, v_bf, xlo_abf);

    // 3) out = attn @ Wo^T + bo (plain fp32 store)
    gemm_out<<<dim3(8, M_ / 128), blk, 0, stream>>>(xlo_abf, wob, bo, out);
}